// Round 1
// baseline (259.921 us; speedup 1.0000x reference)
//
#include <hip/hip_runtime.h>
#include <math.h>

#define BATCH 4
#define SEQ   4096
#define DIM   128
#define NROW  (BATCH*SEQ)

typedef _Float16 f16_t;
typedef _Float16 f16x8 __attribute__((ext_vector_type(8)));
typedef float    f32x4 __attribute__((ext_vector_type(4)));

// softmax scale 1/sqrt(128) and log2(e) folded into Q
#define QSCALE ((float)(1.4426950408889634 / 11.313708498984761))

// ---------------------------------------------------------------------------
// Kernel 1: QKV projection. fp32 accumulate, then split Q,K into f16 hi/lo
// pairs (compensated QK^T later); V stored pre-transposed per batch:
// Vt[b][d][s] so the flash kernel can stage V^T coalesced.
// ---------------------------------------------------------------------------
__global__ __launch_bounds__(256) void proj_kernel(
    const float* __restrict__ x,
    const float* __restrict__ wq, const float* __restrict__ wk,
    const float* __restrict__ wv,
    f16_t* __restrict__ Qh, f16_t* __restrict__ Ql,
    f16_t* __restrict__ Kh, f16_t* __restrict__ Kl,
    f16_t* __restrict__ Vt)
{
    __shared__ float sx[32*128];
    __shared__ f16_t svt[128*34];   // pad 34 -> 2-way-free LDS writes
    const int tid = threadIdx.x;
    const int s0  = blockIdx.x * 32;     // 32 rows per block, 512 blocks

    {   // stage 32 x-rows (16 KB), coalesced float4
        const float4* xg  = (const float4*)(x + (size_t)s0*DIM);
        float4*       sx4 = (float4*)sx;
        #pragma unroll
        for (int i = 0; i < 4; i++) sx4[tid + 256*i] = xg[tid + 256*i];
    }
    __syncthreads();

    const int e  = tid & 127;   // output column
    const int rr = tid >> 7;    // 0/1: row parity (wave-uniform -> LDS broadcast)

    float qa[16], ka[16], va[16];
    #pragma unroll
    for (int i = 0; i < 16; i++) { qa[i]=0.f; ka[i]=0.f; va[i]=0.f; }

    #pragma unroll 4
    for (int d = 0; d < DIM; d++) {
        const float wqv = wq[d*DIM + e];
        const float wkv = wk[d*DIM + e];
        const float wvv = wv[d*DIM + e];
        #pragma unroll
        for (int i = 0; i < 16; i++) {
            const float xv = sx[(rr + 2*i)*DIM + d];
            qa[i] = fmaf(xv, wqv, qa[i]);
            ka[i] = fmaf(xv, wkv, ka[i]);
            va[i] = fmaf(xv, wvv, va[i]);
        }
    }

    const int b = s0 >> 12;
    #pragma unroll
    for (int i = 0; i < 16; i++) {
        const int    r  = rr + 2*i;
        const size_t g  = (size_t)(s0 + r)*DIM + e;
        const float  qs = qa[i] * QSCALE;
        const f16_t  qh = (f16_t)qs;
        Qh[g] = qh;
        Ql[g] = (f16_t)(qs - (float)qh);
        const float  kk = ka[i];
        const f16_t  kh = (f16_t)kk;
        Kh[g] = kh;
        Kl[g] = (f16_t)(kk - (float)kh);
        svt[e*34 + r] = (f16_t)va[i];
    }
    __syncthreads();

    {   // write V^T chunk: Vt[b][e][s0..s0+31], packed 16B stores
        const int e2   = tid >> 1, half = tid & 1;
        const int sloc = s0 & (SEQ-1);
        union { ushort u[16]; uint4 v[2]; } pk;
        #pragma unroll
        for (int j = 0; j < 16; j++)
            pk.u[j] = __builtin_bit_cast(ushort, svt[e2*34 + half*16 + j]);
        uint4* dst = (uint4*)(Vt + ((size_t)b*DIM + e2)*SEQ + sloc + half*16);
        dst[0] = pk.v[0];
        dst[1] = pk.v[1];
    }
}

// ---------------------------------------------------------------------------
// Kernel 2: fused flash attention. 256 blocks (b, qtile), 4 waves/block,
// wave owns 16 Q rows. Iterate 64-row K/V tiles with online softmax.
// QK^T compensated: Qh*Kh + Ql*Kh + Qh*Kl (fp32-accurate logits).
// ---------------------------------------------------------------------------
#define LDK 136   // 64-row K tiles, padded (stride 272B -> 2-way free)
#define LDV 72    // 128-row V^T tile, padded (144B)
#define LDP 72

__global__ __launch_bounds__(256) void flash_kernel(
    const f16_t* __restrict__ Qh, const f16_t* __restrict__ Ql,
    const f16_t* __restrict__ Kh, const f16_t* __restrict__ Kl,
    const f16_t* __restrict__ Vt, float* __restrict__ out)
{
    __shared__ __align__(16) f16_t sKh[64*LDK];
    __shared__ __align__(16) f16_t sKl[64*LDK];
    __shared__ __align__(16) f16_t sVt[128*LDV];
    __shared__ __align__(16) f16_t sP [4*16*LDP];

    const int tid  = threadIdx.x;
    const int wave = tid >> 6;
    const int lane = tid & 63;
    const int quad = lane >> 4;
    const int ln   = lane & 15;

    const int b  = blockIdx.x >> 6;
    const int qt = blockIdx.x & 63;
    const int qrow0 = qt*64 + wave*16;

    // Q fragments (A-layout: row = ln, k = quad*8 + j + 32*ks), held in regs
    f16x8 qhf[4], qlf[4];
    {
        const size_t gq = ((size_t)b*SEQ + qrow0 + ln)*DIM;
        #pragma unroll
        for (int ks = 0; ks < 4; ks++) {
            qhf[ks] = *(const f16x8*)(Qh + gq + quad*8 + ks*32);
            qlf[ks] = *(const f16x8*)(Ql + gq + quad*8 + ks*32);
        }
    }

    f32x4 oacc[8];
    #pragma unroll
    for (int i = 0; i < 8; i++)
        for (int r = 0; r < 4; r++) oacc[i][r] = 0.f;
    float mrun[4], lrun[4];
    #pragma unroll
    for (int r = 0; r < 4; r++) { mrun[r] = -__builtin_inff(); lrun[r] = 0.f; }

    f16_t* sPw = sP + wave*16*LDP;

    for (int kt = 0; kt < SEQ/64; kt++) {
        __syncthreads();   // previous iteration's LDS reads done
        {   // stage K tiles (64x128 h+l) and V^T tile (128x64), coalesced 16B
            const size_t gk = ((size_t)b*SEQ + kt*64)*DIM;
            #pragma unroll
            for (int p = 0; p < 4; p++) {
                const int c = tid + 256*p;
                const int r = c >> 4, dc = c & 15;
                *(float4*)(sKh + r*LDK + dc*8) = *(const float4*)(Kh + gk + r*DIM + dc*8);
                *(float4*)(sKl + r*LDK + dc*8) = *(const float4*)(Kl + gk + r*DIM + dc*8);
            }
            const size_t gv = (size_t)b*DIM*SEQ + kt*64;
            #pragma unroll
            for (int p = 0; p < 4; p++) {
                const int c = tid + 256*p;
                const int dd = c >> 3, j = c & 7;
                *(float4*)(sVt + dd*LDV + j*8) = *(const float4*)(Vt + gv + (size_t)dd*SEQ + j*8);
            }
        }
        __syncthreads();

        // ---- S = Q K^T (compensated), 4 n-blocks = 4 independent chains ----
        f32x4 sacc[4];
        #pragma unroll
        for (int nb = 0; nb < 4; nb++)
            for (int r = 0; r < 4; r++) sacc[nb][r] = 0.f;
        #pragma unroll
        for (int ks = 0; ks < 4; ks++) {
            #pragma unroll
            for (int nb = 0; nb < 4; nb++) {
                const f16x8 khf = *(const f16x8*)(sKh + (nb*16+ln)*LDK + quad*8 + ks*32);
                const f16x8 klf = *(const f16x8*)(sKl + (nb*16+ln)*LDK + quad*8 + ks*32);
                sacc[nb] = __builtin_amdgcn_mfma_f32_16x16x32_f16(qhf[ks], khf, sacc[nb], 0,0,0);
                sacc[nb] = __builtin_amdgcn_mfma_f32_16x16x32_f16(qlf[ks], khf, sacc[nb], 0,0,0);
                sacc[nb] = __builtin_amdgcn_mfma_f32_16x16x32_f16(qhf[ks], klf, sacc[nb], 0,0,0);
            }
        }

        // ---- online softmax (rows = quad*4 + r; reduce over 16 lanes/quad) ----
        float mx[4];
        #pragma unroll
        for (int r = 0; r < 4; r++)
            mx[r] = fmaxf(fmaxf(sacc[0][r], sacc[1][r]), fmaxf(sacc[2][r], sacc[3][r]));
        #pragma unroll
        for (int msk = 1; msk < 16; msk <<= 1)
            for (int r = 0; r < 4; r++) mx[r] = fmaxf(mx[r], __shfl_xor(mx[r], msk, 64));

        float alpha[4], mnew[4];
        #pragma unroll
        for (int r = 0; r < 4; r++) {
            mnew[r]  = fmaxf(mrun[r], mx[r]);
            alpha[r] = exp2f(mrun[r] - mnew[r]);
            mrun[r]  = mnew[r];
        }

        float rs[4] = {0.f, 0.f, 0.f, 0.f};
        #pragma unroll
        for (int nb = 0; nb < 4; nb++) {
            #pragma unroll
            for (int r = 0; r < 4; r++) {
                const float p = exp2f(sacc[nb][r] - mnew[r]);
                rs[r] += p;
                sPw[(quad*4 + r)*LDP + nb*16 + ln] = (f16_t)p;
            }
        }
        #pragma unroll
        for (int msk = 1; msk < 16; msk <<= 1)
            for (int r = 0; r < 4; r++) rs[r] += __shfl_xor(rs[r], msk, 64);
        #pragma unroll
        for (int r = 0; r < 4; r++) lrun[r] = lrun[r]*alpha[r] + rs[r];

        #pragma unroll
        for (int db = 0; db < 8; db++)
            for (int r = 0; r < 4; r++) oacc[db][r] *= alpha[r];

        // P writes are cross-lane consumed within this wave only: drain LDS
        __asm__ volatile("s_waitcnt lgkmcnt(0)" ::: "memory");

        // ---- O += P V ----
        f16x8 pf[2];
        #pragma unroll
        for (int ks = 0; ks < 2; ks++)
            pf[ks] = *(const f16x8*)(sPw + ln*LDP + quad*8 + ks*32);
        #pragma unroll
        for (int db = 0; db < 8; db++) {
            #pragma unroll
            for (int ks = 0; ks < 2; ks++) {
                const f16x8 vf = *(const f16x8*)(sVt + (db*16+ln)*LDV + quad*8 + ks*32);
                oacc[db] = __builtin_amdgcn_mfma_f32_16x16x32_f16(pf[ks], vf, oacc[db], 0,0,0);
            }
        }
    }

    // ---- epilogue: divide by l, store fp32 ----
    float inv[4];
    #pragma unroll
    for (int r = 0; r < 4; r++) inv[r] = 1.f / lrun[r];
    float* ob = out + ((size_t)b*SEQ + qrow0)*DIM;
    #pragma unroll
    for (int db = 0; db < 8; db++)
        for (int r = 0; r < 4; r++)
            ob[(quad*4 + r)*DIM + db*16 + ln] = oacc[db][r]*inv[r];
}

// ---------------------------------------------------------------------------
extern "C" void kernel_launch(void* const* d_in, const int* in_sizes, int n_in,
                              void* d_out, int out_size, void* d_ws, size_t ws_size,
                              hipStream_t stream) {
    const float* x  = (const float*)d_in[0];
    // d_in[1] = token_attention_masks (unused: reference applies softmax to
    // the UNMASKED scores)
    const float* wq = (const float*)d_in[2];
    const float* wk = (const float*)d_in[3];
    const float* wv = (const float*)d_in[4];

    f16_t* ws = (f16_t*)d_ws;                 // 5 x 4 MB f16 arrays = 20 MB
    f16_t* Qh = ws;
    f16_t* Ql = Qh + (size_t)NROW*DIM;
    f16_t* Kh = Ql + (size_t)NROW*DIM;
    f16_t* Kl = Kh + (size_t)NROW*DIM;
    f16_t* Vt = Kl + (size_t)NROW*DIM;        // [BATCH][DIM][SEQ]

    proj_kernel<<<NROW/32, 256, 0, stream>>>(x, wq, wk, wv, Qh, Ql, Kh, Kl, Vt);
    flash_kernel<<<BATCH*(SEQ/64), 256, 0, stream>>>(Qh, Ql, Kh, Kl, Vt, (float*)d_out);
}

// Round 3
// 200.232 us; speedup vs baseline: 1.2981x; 1.2981x over previous
//
#include <hip/hip_runtime.h>
#include <math.h>

#define BATCH  4
#define SEQ    4096
#define DIM    128
#define NROW   (BATCH*SEQ)
#define NSPLIT 4
#define NW     384   // concatenated W cols (q|k|v)

typedef _Float16 f16_t;
typedef _Float16 f16x4 __attribute__((ext_vector_type(4)));
typedef _Float16 f16x8 __attribute__((ext_vector_type(8)));
typedef float    f32x4 __attribute__((ext_vector_type(4)));

// softmax scale 1/sqrt(128) and log2(e) folded into Q
#define QSCALE ((float)(1.4426950408889634 / 11.313708498984761))

// ---- DPP 16-lane-row allreduce (pure VALU, keeps reductions off LDS pipe) ----
template<int CTRL>
__device__ __forceinline__ float dpp_mov(float x) {
    return __builtin_bit_cast(float,
        __builtin_amdgcn_update_dpp(0, __builtin_bit_cast(int, x), CTRL, 0xF, 0xF, true));
}
__device__ __forceinline__ float rowsum16(float x) {
    x += dpp_mov<0x121>(x);   // row_ror:1
    x += dpp_mov<0x122>(x);   // row_ror:2
    x += dpp_mov<0x124>(x);   // row_ror:4
    x += dpp_mov<0x128>(x);   // row_ror:8
    return x;
}
__device__ __forceinline__ float rowmax16(float x) {
    x = fmaxf(x, dpp_mov<0x121>(x));
    x = fmaxf(x, dpp_mov<0x122>(x));
    x = fmaxf(x, dpp_mov<0x124>(x));
    x = fmaxf(x, dpp_mov<0x128>(x));
    return x;
}

// ---------------------------------------------------------------------------
// Kernel 0: transpose+hi/lo-split W once: Wt[n][k] = W[k][n] as f16 h/l.
// ---------------------------------------------------------------------------
__global__ __launch_bounds__(256) void wsplit_kernel(
    const float* __restrict__ wq, const float* __restrict__ wk,
    const float* __restrict__ wv,
    f16_t* __restrict__ Wth, f16_t* __restrict__ Wtl)
{
    const int idx = blockIdx.x*256 + threadIdx.x;   // 49152 = 384*128
    const int n = idx >> 7;
    const int k = idx & 127;
    const int mat = n >> 7, col = n & 127;
    const float* w = (mat == 0) ? wq : ((mat == 1) ? wk : wv);
    const float v = w[k*DIM + col];
    const f16_t h = (f16_t)v;
    Wth[idx] = h;                       // Wth[n*128 + k]
    Wtl[idx] = (f16_t)(v - (float)h);
}

// ---------------------------------------------------------------------------
// Kernel 1: QKV projection as MFMA GEMM. C = X*W with X,W hi/lo f16 split,
// 3-term compensation (Xh*Wh + Xl*Wh + Xh*Wl) -> ~fp32-accurate.
// Block: 64 M-rows x 128 N-cols, K=128 in two 64-phases. nt picks Q/K/V.
// ---------------------------------------------------------------------------
#define LDX 72    // padded LDS stride (144B, 16B-aligned, conflict-free b128)

__global__ __launch_bounds__(256) void proj_kernel(
    const float* __restrict__ x,
    const f16_t* __restrict__ Wth, const f16_t* __restrict__ Wtl,
    f16_t* __restrict__ Qh, f16_t* __restrict__ Ql,
    f16_t* __restrict__ Kh, f16_t* __restrict__ Kl,
    f16_t* __restrict__ Vt)
{
    __shared__ __align__(16) f16_t smem[(64 + 64 + 128 + 128) * LDX]; // 54 KB
    f16_t* sXh = smem;
    f16_t* sXl = smem + 64*LDX;
    f16_t* sWh = smem + 128*LDX;
    f16_t* sWl = smem + 256*LDX;

    const int tid  = threadIdx.x;
    const int wave = tid >> 6;
    const int lane = tid & 63;
    const int quad = lane >> 4;
    const int ln   = lane & 15;

    const int nt = blockIdx.x % 3;          // 0=Q 1=K 2=V
    const int mb = blockIdx.x / 3;
    const int m0 = mb * 64;
    const int n0 = nt * 128;

    f32x4 acc[8];
    #pragma unroll
    for (int nb = 0; nb < 8; nb++)
        for (int r = 0; r < 4; r++) acc[nb][r] = 0.f;

    #pragma unroll
    for (int ph = 0; ph < 2; ph++) {
        __syncthreads();
        // stage X 64x64 fp32 -> h/l
        #pragma unroll
        for (int i = 0; i < 4; i++) {
            const int idx = tid + 256*i;
            const int r = idx >> 4, f4 = idx & 15;
            const float4 v = *(const float4*)(x + (size_t)(m0+r)*DIM + ph*64 + f4*4);
            f16_t h0=(f16_t)v.x, h1=(f16_t)v.y, h2=(f16_t)v.z, h3=(f16_t)v.w;
            *(f16x4*)(sXh + r*LDX + f4*4) = (f16x4){h0,h1,h2,h3};
            *(f16x4*)(sXl + r*LDX + f4*4) =
                (f16x4){(f16_t)(v.x-(float)h0),(f16_t)(v.y-(float)h1),
                        (f16_t)(v.z-(float)h2),(f16_t)(v.w-(float)h3)};
        }
        // stage W^T 128n x 64k f16 h/l (pre-split by wsplit_kernel)
        #pragma unroll
        for (int i = 0; i < 4; i++) {
            const int idx = tid + 256*i;
            const int n = idx >> 3, g = idx & 7;
            *(uint4*)(sWh + n*LDX + g*8) =
                *(const uint4*)(Wth + (size_t)(n0+n)*DIM + ph*64 + g*8);
            *(uint4*)(sWl + n*LDX + g*8) =
                *(const uint4*)(Wtl + (size_t)(n0+n)*DIM + ph*64 + g*8);
        }
        __syncthreads();

        f16x8 ah[2], al[2];
        #pragma unroll
        for (int ks = 0; ks < 2; ks++) {
            ah[ks] = *(const f16x8*)(sXh + (wave*16+ln)*LDX + quad*8 + ks*32);
            al[ks] = *(const f16x8*)(sXl + (wave*16+ln)*LDX + quad*8 + ks*32);
        }
        #pragma unroll
        for (int nb = 0; nb < 8; nb++) {
            #pragma unroll
            for (int ks = 0; ks < 2; ks++) {
                const f16x8 bh = *(const f16x8*)(sWh + (nb*16+ln)*LDX + quad*8 + ks*32);
                const f16x8 bl = *(const f16x8*)(sWl + (nb*16+ln)*LDX + quad*8 + ks*32);
                acc[nb] = __builtin_amdgcn_mfma_f32_16x16x32_f16(ah[ks], bh, acc[nb], 0,0,0);
                acc[nb] = __builtin_amdgcn_mfma_f32_16x16x32_f16(al[ks], bh, acc[nb], 0,0,0);
                acc[nb] = __builtin_amdgcn_mfma_f32_16x16x32_f16(ah[ks], bl, acc[nb], 0,0,0);
            }
        }
    }

    // epilogue
    const int rowl = wave*16 + quad*4;      // + r
    if (nt == 0) {
        #pragma unroll
        for (int nb = 0; nb < 8; nb++)
            for (int r = 0; r < 4; r++) {
                const size_t g = (size_t)(m0 + rowl + r)*DIM + nb*16 + ln;
                const float  v = acc[nb][r] * QSCALE;
                const f16_t  h = (f16_t)v;
                Qh[g] = h; Ql[g] = (f16_t)(v - (float)h);
            }
    } else if (nt == 1) {
        #pragma unroll
        for (int nb = 0; nb < 8; nb++)
            for (int r = 0; r < 4; r++) {
                const size_t g = (size_t)(m0 + rowl + r)*DIM + nb*16 + ln;
                const float  v = acc[nb][r];
                const f16_t  h = (f16_t)v;
                Kh[g] = h; Kl[g] = (f16_t)(v - (float)h);
            }
    }
    // V: transpose through LDS (reuse sX region), write Vt[b][d][s]
    __syncthreads();
    if (nt == 2) {
        f16_t* svt = smem;                  // 128 x LDX, [d][s_local]
        #pragma unroll
        for (int nb = 0; nb < 8; nb++)
            for (int r = 0; r < 4; r++)
                svt[(nb*16+ln)*LDX + rowl + r] = (f16_t)acc[nb][r];
    }
    __syncthreads();
    if (nt == 2) {
        const f16_t* svt = smem;
        const int bb = m0 >> 12, sloc = m0 & (SEQ-1);
        const int d = tid >> 1, half = tid & 1;
        // each (d, half) thread covers 32 contiguous s-elements = 4 x uint4
        #pragma unroll
        for (int q = 0; q < 4; q++) {
            *(uint4*)(Vt + ((size_t)bb*DIM + d)*SEQ + sloc + half*32 + q*8) =
                *(const uint4*)(svt + d*LDX + half*32 + q*8);
        }
    }
}

// ---------------------------------------------------------------------------
// Kernel 2: fused flash attention, KV-split=4. 512 blocks, 4 waves/block,
// wave owns 32 Q rows (2 m-tiles sharing every K/V B-fragment -> half the
// LDS read traffic). Compensated QK^T: Qh*Kh + Ql*Kh + Qh*Kl.
// ---------------------------------------------------------------------------
#define LDK 136
#define LDV 72
#define LDP 72

__global__ __launch_bounds__(256, 2) void flash_kernel(
    const f16_t* __restrict__ Qh, const f16_t* __restrict__ Ql,
    const f16_t* __restrict__ Kh, const f16_t* __restrict__ Kl,
    const f16_t* __restrict__ Vt,
    f16_t* __restrict__ Opart, float2* __restrict__ mlbuf)
{
    __shared__ __align__(16) f16_t sKh[64*LDK];
    __shared__ __align__(16) f16_t sKl[64*LDK];
    __shared__ __align__(16) f16_t sVt[128*LDV];
    __shared__ __align__(16) f16_t sP [4*16*LDP];   // one 16-row buf per wave

    const int tid  = threadIdx.x;
    const int wave = tid >> 6;
    const int lane = tid & 63;
    const int quad = lane >> 4;
    const int ln   = lane & 15;

    const int bq = blockIdx.x >> 2;     // 0..127
    const int sp = blockIdx.x & 3;      // KV split
    const int b  = bq >> 5;
    const int qt = bq & 31;
    const int qrow0 = qt*128 + wave*32;

    f16x8 qhf[2][4], qlf[2][4];
    #pragma unroll
    for (int mt = 0; mt < 2; mt++) {
        const size_t gq = ((size_t)b*SEQ + qrow0 + mt*16 + ln)*DIM;
        #pragma unroll
        for (int ks = 0; ks < 4; ks++) {
            qhf[mt][ks] = *(const f16x8*)(Qh + gq + quad*8 + ks*32);
            qlf[mt][ks] = *(const f16x8*)(Ql + gq + quad*8 + ks*32);
        }
    }

    f32x4 oacc[2][8];
    #pragma unroll
    for (int mt = 0; mt < 2; mt++)
        for (int db = 0; db < 8; db++)
            for (int r = 0; r < 4; r++) oacc[mt][db][r] = 0.f;
    float mrun[2][4], lrun[2][4];
    #pragma unroll
    for (int mt = 0; mt < 2; mt++)
        for (int r = 0; r < 4; r++) { mrun[mt][r] = -__builtin_inff(); lrun[mt][r] = 0.f; }

    f16_t* sPw = sP + wave*16*LDP;

    for (int kt = sp*16; kt < sp*16 + 16; kt++) {
        __syncthreads();
        {   // stage K h/l (64x128) and V^T (128x64), coalesced 16B
            const size_t gk = ((size_t)b*SEQ + kt*64)*DIM;
            #pragma unroll
            for (int p = 0; p < 4; p++) {
                const int c = tid + 256*p;
                const int r = c >> 4, dc = c & 15;
                *(float4*)(sKh + r*LDK + dc*8) = *(const float4*)(Kh + gk + r*DIM + dc*8);
                *(float4*)(sKl + r*LDK + dc*8) = *(const float4*)(Kl + gk + r*DIM + dc*8);
            }
            const size_t gv = (size_t)b*DIM*SEQ + kt*64;
            #pragma unroll
            for (int p = 0; p < 4; p++) {
                const int c = tid + 256*p;
                const int dd = c >> 3, j = c & 7;
                *(float4*)(sVt + dd*LDV + j*8) = *(const float4*)(Vt + gv + (size_t)dd*SEQ + j*8);
            }
        }
        __syncthreads();

        // ---- S = Q K^T, both m-tiles share each K fragment ----
        f32x4 sacc[2][4];
        #pragma unroll
        for (int mt = 0; mt < 2; mt++)
            for (int nb = 0; nb < 4; nb++)
                for (int r = 0; r < 4; r++) sacc[mt][nb][r] = 0.f;
        #pragma unroll
        for (int ks = 0; ks < 4; ks++) {
            #pragma unroll
            for (int nb = 0; nb < 4; nb++) {
                const f16x8 khf = *(const f16x8*)(sKh + (nb*16+ln)*LDK + quad*8 + ks*32);
                const f16x8 klf = *(const f16x8*)(sKl + (nb*16+ln)*LDK + quad*8 + ks*32);
                sacc[0][nb] = __builtin_amdgcn_mfma_f32_16x16x32_f16(qhf[0][ks], khf, sacc[0][nb], 0,0,0);
                sacc[0][nb] = __builtin_amdgcn_mfma_f32_16x16x32_f16(qlf[0][ks], khf, sacc[0][nb], 0,0,0);
                sacc[0][nb] = __builtin_amdgcn_mfma_f32_16x16x32_f16(qhf[0][ks], klf, sacc[0][nb], 0,0,0);
                sacc[1][nb] = __builtin_amdgcn_mfma_f32_16x16x32_f16(qhf[1][ks], khf, sacc[1][nb], 0,0,0);
                sacc[1][nb] = __builtin_amdgcn_mfma_f32_16x16x32_f16(qlf[1][ks], khf, sacc[1][nb], 0,0,0);
                sacc[1][nb] = __builtin_amdgcn_mfma_f32_16x16x32_f16(qhf[1][ks], klf, sacc[1][nb], 0,0,0);
            }
        }

        // ---- online softmax per m-tile (DPP reductions, P via wave-local LDS) ----
        f16x8 pf[2][2];
        #pragma unroll
        for (int mt = 0; mt < 2; mt++) {
            float mx[4];
            #pragma unroll
            for (int r = 0; r < 4; r++) {
                mx[r] = fmaxf(fmaxf(sacc[mt][0][r], sacc[mt][1][r]),
                              fmaxf(sacc[mt][2][r], sacc[mt][3][r]));
                mx[r] = rowmax16(mx[r]);
            }
            float alpha[4], mnew[4];
            #pragma unroll
            for (int r = 0; r < 4; r++) {
                mnew[r]  = fmaxf(mrun[mt][r], mx[r]);
                alpha[r] = exp2f(mrun[mt][r] - mnew[r]);
                mrun[mt][r] = mnew[r];
            }
            float rs[4] = {0.f,0.f,0.f,0.f};
            #pragma unroll
            for (int nb = 0; nb < 4; nb++)
                for (int r = 0; r < 4; r++) {
                    const float p = exp2f(sacc[mt][nb][r] - mnew[r]);
                    rs[r] += p;
                    sPw[(quad*4 + r)*LDP + nb*16 + ln] = (f16_t)p;
                }
            #pragma unroll
            for (int r = 0; r < 4; r++) {
                rs[r] = rowsum16(rs[r]);
                lrun[mt][r] = lrun[mt][r]*alpha[r] + rs[r];
            }
            #pragma unroll
            for (int db = 0; db < 8; db++)
                for (int r = 0; r < 4; r++) oacc[mt][db][r] *= alpha[r];

            // wave-local P round-trip; DS ops are in-order per wave, so the
            // next m-tile's writes can't pass these reads.
            __asm__ volatile("s_waitcnt lgkmcnt(0)" ::: "memory");
            pf[mt][0] = *(const f16x8*)(sPw + ln*LDP + quad*8);
            pf[mt][1] = *(const f16x8*)(sPw + ln*LDP + quad*8 + 32);
        }

        // ---- O += P V, V fragment shared by both m-tiles ----
        #pragma unroll
        for (int db = 0; db < 8; db++) {
            #pragma unroll
            for (int ks = 0; ks < 2; ks++) {
                const f16x8 vf = *(const f16x8*)(sVt + (db*16+ln)*LDV + quad*8 + ks*32);
                oacc[0][db] = __builtin_amdgcn_mfma_f32_16x16x32_f16(pf[0][ks], vf, oacc[0][db], 0,0,0);
                oacc[1][db] = __builtin_amdgcn_mfma_f32_16x16x32_f16(pf[1][ks], vf, oacc[1][db], 0,0,0);
            }
        }
    }

    // ---- epilogue: normalized partial (f16) + (m,l) per row ----
    #pragma unroll
    for (int mt = 0; mt < 2; mt++) {
        #pragma unroll
        for (int r = 0; r < 4; r++) {
            const int row = b*SEQ + qrow0 + mt*16 + quad*4 + r;
            const float inv = 1.f / lrun[mt][r];
            f16_t* ob = Opart + ((size_t)sp*NROW + row)*DIM;
            #pragma unroll
            for (int db = 0; db < 8; db++)
                ob[db*16 + ln] = (f16_t)(oacc[mt][db][r] * inv);
            if (ln == 0)
                mlbuf[sp*NROW + row] = make_float2(mrun[mt][r], lrun[mt][r]);
        }
    }
}

// ---------------------------------------------------------------------------
// Kernel 3: combine the 4 KV-split partials.
// ---------------------------------------------------------------------------
__global__ __launch_bounds__(256) void combine_kernel(
    const f16_t* __restrict__ Opart, const float2* __restrict__ mlbuf,
    float* __restrict__ out)
{
    const int idx = blockIdx.x*256 + threadIdx.x;   // 262144
    const int row = idx >> 4;
    const int d0  = (idx & 15) * 8;

    float m[NSPLIT], l[NSPLIT];
    #pragma unroll
    for (int s = 0; s < NSPLIT; s++) {
        const float2 v = mlbuf[s*NROW + row];
        m[s] = v.x; l[s] = v.y;
    }
    float M = fmaxf(fmaxf(m[0], m[1]), fmaxf(m[2], m[3]));
    float w[NSPLIT], denom = 0.f;
    #pragma unroll
    for (int s = 0; s < NSPLIT; s++) { w[s] = l[s] * exp2f(m[s] - M); denom += w[s]; }
    const float inv = 1.f / denom;

    float o[8] = {0,0,0,0,0,0,0,0};
    #pragma unroll
    for (int s = 0; s < NSPLIT; s++) {
        const f16x8 v = *(const f16x8*)(Opart + ((size_t)s*NROW + row)*DIM + d0);
        const float ws = w[s] * inv;
        #pragma unroll
        for (int j = 0; j < 8; j++) o[j] += ws * (float)v[j];
    }
    float* ob = out + (size_t)row*DIM + d0;
    *(float4*)(ob)     = make_float4(o[0], o[1], o[2], o[3]);
    *(float4*)(ob + 4) = make_float4(o[4], o[5], o[6], o[7]);
}

// ---------------------------------------------------------------------------
extern "C" void kernel_launch(void* const* d_in, const int* in_sizes, int n_in,
                              void* d_out, int out_size, void* d_ws, size_t ws_size,
                              hipStream_t stream) {
    const float* x  = (const float*)d_in[0];
    // d_in[1] = token_attention_masks (unused: reference softmaxes UNMASKED scores)
    const float* wq = (const float*)d_in[2];
    const float* wk = (const float*)d_in[3];
    const float* wv = (const float*)d_in[4];

    f16_t* ws = (f16_t*)d_ws;
    f16_t* Qh    = ws;                                    // 2097152 each
    f16_t* Ql    = Qh  + (size_t)NROW*DIM;
    f16_t* Kh    = Ql  + (size_t)NROW*DIM;
    f16_t* Kl    = Kh  + (size_t)NROW*DIM;
    f16_t* Vt    = Kl  + (size_t)NROW*DIM;                // [B][D][S]
    f16_t* Wth   = Vt  + (size_t)NROW*DIM;                // 49152 each
    f16_t* Wtl   = Wth + (size_t)NW*DIM;
    f16_t* Opart = Wtl + (size_t)NW*DIM;                  // 4 x NROW x DIM
    float2* mlbuf = (float2*)(Opart + (size_t)NSPLIT*NROW*DIM);

    wsplit_kernel <<<NW*DIM/256,        256, 0, stream>>>(wq, wk, wv, Wth, Wtl);
    proj_kernel   <<<(NROW/64)*3,       256, 0, stream>>>(x, Wth, Wtl, Qh, Ql, Kh, Kl, Vt);
    flash_kernel  <<<BATCH*32*NSPLIT,   256, 0, stream>>>(Qh, Ql, Kh, Kl, Vt, Opart, mlbuf);
    combine_kernel<<<NROW*DIM/8/256,    256, 0, stream>>>(Opart, mlbuf, (float*)d_out);
}

// Round 4
// 189.907 us; speedup vs baseline: 1.3687x; 1.0544x over previous
//
#include <hip/hip_runtime.h>
#include <math.h>

#define BATCH  4
#define SEQ    4096
#define DIM    128
#define NROW   (BATCH*SEQ)
#define NSPLIT 4
#define NW     384   // concatenated W cols (q|k|v)

typedef _Float16 f16_t;
typedef _Float16 f16x4 __attribute__((ext_vector_type(4)));
typedef _Float16 f16x8 __attribute__((ext_vector_type(8)));
typedef float    f32x4 __attribute__((ext_vector_type(4)));

// softmax scale 1/sqrt(128) and log2(e) folded into Q
#define QSCALE ((float)(1.4426950408889634 / 11.313708498984761))

// ---- DPP 16-lane-row allreduce (pure VALU, keeps reductions off LDS pipe) ----
template<int CTRL>
__device__ __forceinline__ float dpp_mov(float x) {
    return __builtin_bit_cast(float,
        __builtin_amdgcn_update_dpp(0, __builtin_bit_cast(int, x), CTRL, 0xF, 0xF, true));
}
__device__ __forceinline__ float rowsum16(float x) {
    x += dpp_mov<0x121>(x);
    x += dpp_mov<0x122>(x);
    x += dpp_mov<0x124>(x);
    x += dpp_mov<0x128>(x);
    return x;
}
__device__ __forceinline__ float rowmax16(float x) {
    x = fmaxf(x, dpp_mov<0x121>(x));
    x = fmaxf(x, dpp_mov<0x122>(x));
    x = fmaxf(x, dpp_mov<0x124>(x));
    x = fmaxf(x, dpp_mov<0x128>(x));
    return x;
}

// ---------------------------------------------------------------------------
// Kernel 0: transpose+hi/lo-split W once: Wt[n][k] = W[k][n] as f16 h/l.
// ---------------------------------------------------------------------------
__global__ __launch_bounds__(256) void wsplit_kernel(
    const float* __restrict__ wq, const float* __restrict__ wk,
    const float* __restrict__ wv,
    f16_t* __restrict__ Wth, f16_t* __restrict__ Wtl)
{
    const int idx = blockIdx.x*256 + threadIdx.x;   // 49152 = 384*128
    const int n = idx >> 7;
    const int k = idx & 127;
    const int mat = n >> 7, col = n & 127;
    const float* w = (mat == 0) ? wq : ((mat == 1) ? wk : wv);
    const float v = w[k*DIM + col];
    const f16_t h = (f16_t)v;
    Wth[idx] = h;
    Wtl[idx] = (f16_t)(v - (float)h);
}

// ---------------------------------------------------------------------------
// Kernel 1: QKV projection as MFMA GEMM (3-term compensated, fp32-accurate).
// Epilogue: C-layout -> swizzled LDS -> b128 coalesced global stores.
// ---------------------------------------------------------------------------
#define LDX 72    // staging stride (144B)
#define LDE 136   // epilogue transpose stride (272B)

__global__ __launch_bounds__(256) void proj_kernel(
    const float* __restrict__ x,
    const f16_t* __restrict__ Wth, const f16_t* __restrict__ Wtl,
    f16_t* __restrict__ Qh, f16_t* __restrict__ Ql,
    f16_t* __restrict__ Kh, f16_t* __restrict__ Vt)
{
    __shared__ __align__(16) f16_t smem[(64 + 64 + 128 + 128) * LDX]; // 55296 B
    f16_t* sXh = smem;
    f16_t* sXl = smem + 64*LDX;
    f16_t* sWh = smem + 128*LDX;
    f16_t* sWl = smem + 256*LDX;

    const int tid  = threadIdx.x;
    const int wave = tid >> 6;
    const int lane = tid & 63;
    const int quad = lane >> 4;
    const int ln   = lane & 15;

    const int nt = blockIdx.x % 3;          // 0=Q 1=K 2=V
    const int mb = blockIdx.x / 3;
    const int m0 = mb * 64;
    const int n0 = nt * 128;

    f32x4 acc[8];
    #pragma unroll
    for (int nb = 0; nb < 8; nb++)
        for (int r = 0; r < 4; r++) acc[nb][r] = 0.f;

    #pragma unroll
    for (int ph = 0; ph < 2; ph++) {
        __syncthreads();
        #pragma unroll
        for (int i = 0; i < 4; i++) {
            const int idx = tid + 256*i;
            const int r = idx >> 4, f4 = idx & 15;
            const float4 v = *(const float4*)(x + (size_t)(m0+r)*DIM + ph*64 + f4*4);
            f16_t h0=(f16_t)v.x, h1=(f16_t)v.y, h2=(f16_t)v.z, h3=(f16_t)v.w;
            *(f16x4*)(sXh + r*LDX + f4*4) = (f16x4){h0,h1,h2,h3};
            *(f16x4*)(sXl + r*LDX + f4*4) =
                (f16x4){(f16_t)(v.x-(float)h0),(f16_t)(v.y-(float)h1),
                        (f16_t)(v.z-(float)h2),(f16_t)(v.w-(float)h3)};
        }
        #pragma unroll
        for (int i = 0; i < 4; i++) {
            const int idx = tid + 256*i;
            const int n = idx >> 3, g = idx & 7;
            *(uint4*)(sWh + n*LDX + g*8) =
                *(const uint4*)(Wth + (size_t)(n0+n)*DIM + ph*64 + g*8);
            *(uint4*)(sWl + n*LDX + g*8) =
                *(const uint4*)(Wtl + (size_t)(n0+n)*DIM + ph*64 + g*8);
        }
        __syncthreads();

        f16x8 ah[2], al[2];
        #pragma unroll
        for (int ks = 0; ks < 2; ks++) {
            ah[ks] = *(const f16x8*)(sXh + (wave*16+ln)*LDX + quad*8 + ks*32);
            al[ks] = *(const f16x8*)(sXl + (wave*16+ln)*LDX + quad*8 + ks*32);
        }
        #pragma unroll
        for (int nb = 0; nb < 8; nb++) {
            #pragma unroll
            for (int ks = 0; ks < 2; ks++) {
                const f16x8 bh = *(const f16x8*)(sWh + (nb*16+ln)*LDX + quad*8 + ks*32);
                const f16x8 bl = *(const f16x8*)(sWl + (nb*16+ln)*LDX + quad*8 + ks*32);
                acc[nb] = __builtin_amdgcn_mfma_f32_16x16x32_f16(ah[ks], bh, acc[nb], 0,0,0);
                acc[nb] = __builtin_amdgcn_mfma_f32_16x16x32_f16(al[ks], bh, acc[nb], 0,0,0);
                acc[nb] = __builtin_amdgcn_mfma_f32_16x16x32_f16(ah[ks], bl, acc[nb], 0,0,0);
            }
        }
    }

    __syncthreads();   // done with staging LDS

    if (nt != 2) {
        // ---- Q/K epilogue: swizzled LDS transpose -> coalesced b128 stores ----
        const float scale = (nt == 0) ? QSCALE : 1.0f;
        f16_t* dsth = (nt == 0) ? Qh : Kh;
        f16_t* sH = smem;             // 64 x LDE
        f16_t* sL = smem + 64*LDE;    // 64 x LDE  (34816 B total)
        #pragma unroll
        for (int nb = 0; nb < 8; nb++)
            #pragma unroll
            for (int r = 0; r < 4; r++) {
                const int row  = wave*16 + quad*4 + r;
                const int colp = (nb*16 + ln) ^ (quad << 4);
                const float v  = acc[nb][r] * scale;
                const f16_t h  = (f16_t)v;
                sH[row*LDE + colp] = h;
                if (nt == 0) sL[row*LDE + colp] = (f16_t)(v - (float)h);
            }
        __syncthreads();
        #pragma unroll
        for (int jj = 0; jj < 4; jj++) {
            const int c    = tid + 256*jj;
            const int row  = c >> 4;
            const int col  = (c & 15) * 8;
            const int colp = col ^ (((row >> 2) & 3) << 4);
            const size_t g = (size_t)(m0 + row)*DIM + col;
            *(uint4*)(dsth + g) = *(const uint4*)(sH + row*LDE + colp);
            if (nt == 0)
                *(uint4*)(Ql + g) = *(const uint4*)(sL + row*LDE + colp);
        }
    } else {
        // ---- V epilogue: transpose to Vt[b][d][s] ----
        f16_t* svt = smem;                  // 128 x LDX, [d][s_local]
        const int rowl = wave*16 + quad*4;
        #pragma unroll
        for (int nb = 0; nb < 8; nb++)
            for (int r = 0; r < 4; r++)
                svt[(nb*16+ln)*LDX + rowl + r] = (f16_t)acc[nb][r];
        __syncthreads();
        const int bb = m0 >> 12, sloc = m0 & (SEQ-1);
        const int d = tid >> 1, half = tid & 1;
        #pragma unroll
        for (int q = 0; q < 4; q++) {
            *(uint4*)(Vt + ((size_t)bb*DIM + d)*SEQ + sloc + half*32 + q*8) =
                *(const uint4*)(svt + d*LDX + half*32 + q*8);
        }
    }
}

// ---------------------------------------------------------------------------
// Kernel 2: fused flash attention, KV-split=4, 2-term compensated QK^T
// (Qh*Kh + Ql*Kh = Q*Kh; Kl term dropped -> K h-only staged).
// Register double-buffer prefetch of K/V tiles; XOR-swizzled P buffer;
// coalesced b128 Opart epilogue via LDS.
// ---------------------------------------------------------------------------
#define LDK 136
#define LDV 72
#define LDP 72
#define LDO 136

__global__ __launch_bounds__(256, 2) void flash_kernel(
    const f16_t* __restrict__ Qh, const f16_t* __restrict__ Ql,
    const f16_t* __restrict__ Kh, const f16_t* __restrict__ Vt,
    f16_t* __restrict__ Opart, float2* __restrict__ mlbuf)
{
    __shared__ __align__(16) f16_t smem[64*LDK + 128*LDV + 4*16*LDP]; // 45056 B
    f16_t* sKh = smem;
    f16_t* sVt = smem + 64*LDK;
    f16_t* sP  = smem + 64*LDK + 128*LDV;
    f16_t* sO  = smem;   // epilogue reuse: 4 waves x 32 x LDO = 17408 f16

    const int tid  = threadIdx.x;
    const int wave = tid >> 6;
    const int lane = tid & 63;
    const int quad = lane >> 4;
    const int ln   = lane & 15;

    const int bq = blockIdx.x >> 2;
    const int sp = blockIdx.x & 3;
    const int b  = bq >> 5;
    const int qt = bq & 31;
    const int qrow0 = qt*128 + wave*32;

    f16x8 qhf[2][4], qlf[2][4];
    #pragma unroll
    for (int mt = 0; mt < 2; mt++) {
        const size_t gq = ((size_t)b*SEQ + qrow0 + mt*16 + ln)*DIM;
        #pragma unroll
        for (int ks = 0; ks < 4; ks++) {
            qhf[mt][ks] = *(const f16x8*)(Qh + gq + quad*8 + ks*32);
            qlf[mt][ks] = *(const f16x8*)(Ql + gq + quad*8 + ks*32);
        }
    }

    f32x4 oacc[2][8];
    #pragma unroll
    for (int mt = 0; mt < 2; mt++)
        for (int db = 0; db < 8; db++)
            for (int r = 0; r < 4; r++) oacc[mt][db][r] = 0.f;
    float mrun[2][4], lrun[2][4];
    #pragma unroll
    for (int mt = 0; mt < 2; mt++)
        for (int r = 0; r < 4; r++) { mrun[mt][r] = -__builtin_inff(); lrun[mt][r] = 0.f; }

    f16_t* sPw = sP + wave*16*LDP;

    // staging chunk coordinates (fixed per thread)
    const int kr[4] = { (tid      ) >> 4, (tid+256) >> 4, (tid+512) >> 4, (tid+768) >> 4 };
    const int kc    = (tid & 15) * 8;
    const int vd[4] = { (tid      ) >> 3, (tid+256) >> 3, (tid+512) >> 3, (tid+768) >> 3 };
    const int vj    = (tid & 7) * 8;

    const f16_t* gKbase = Kh + (size_t)b*SEQ*DIM;
    const f16_t* gVbase = Vt + (size_t)b*DIM*SEQ;

    float4 pk[4], pv[4];
    auto load_tile = [&](int kt) {
        const f16_t* gk = gKbase + (size_t)kt*64*DIM;
        const f16_t* gv = gVbase + kt*64;
        #pragma unroll
        for (int p = 0; p < 4; p++) pk[p] = *(const float4*)(gk + kr[p]*DIM + kc);
        #pragma unroll
        for (int p = 0; p < 4; p++) pv[p] = *(const float4*)(gv + (size_t)vd[p]*SEQ + vj);
    };

    const int kt0 = sp*16, kend = sp*16 + 16;
    load_tile(kt0);

    for (int kt = kt0; kt < kend; kt++) {
        __syncthreads();   // previous iteration's LDS reads done
        #pragma unroll
        for (int p = 0; p < 4; p++) *(float4*)(sKh + kr[p]*LDK + kc) = pk[p];
        #pragma unroll
        for (int p = 0; p < 4; p++) *(float4*)(sVt + vd[p]*LDV + vj) = pv[p];
        if (kt + 1 < kend) load_tile(kt + 1);   // prefetch next tile into regs
        __syncthreads();

        // ---- S = Q K^T (2-term: (Qh+Ql)*Kh), both m-tiles share K frags ----
        f32x4 sacc[2][4];
        #pragma unroll
        for (int mt = 0; mt < 2; mt++)
            for (int nb = 0; nb < 4; nb++)
                for (int r = 0; r < 4; r++) sacc[mt][nb][r] = 0.f;
        #pragma unroll
        for (int ks = 0; ks < 4; ks++) {
            #pragma unroll
            for (int nb = 0; nb < 4; nb++) {
                const f16x8 khf = *(const f16x8*)(sKh + (nb*16+ln)*LDK + quad*8 + ks*32);
                sacc[0][nb] = __builtin_amdgcn_mfma_f32_16x16x32_f16(qhf[0][ks], khf, sacc[0][nb], 0,0,0);
                sacc[1][nb] = __builtin_amdgcn_mfma_f32_16x16x32_f16(qhf[1][ks], khf, sacc[1][nb], 0,0,0);
                sacc[0][nb] = __builtin_amdgcn_mfma_f32_16x16x32_f16(qlf[0][ks], khf, sacc[0][nb], 0,0,0);
                sacc[1][nb] = __builtin_amdgcn_mfma_f32_16x16x32_f16(qlf[1][ks], khf, sacc[1][nb], 0,0,0);
            }
        }

        // ---- online softmax per m-tile ----
        f16x8 pf[2][2];
        #pragma unroll
        for (int mt = 0; mt < 2; mt++) {
            float mx[4];
            #pragma unroll
            for (int r = 0; r < 4; r++) {
                mx[r] = fmaxf(fmaxf(sacc[mt][0][r], sacc[mt][1][r]),
                              fmaxf(sacc[mt][2][r], sacc[mt][3][r]));
                mx[r] = rowmax16(mx[r]);
            }
            float alpha[4], mnew[4];
            #pragma unroll
            for (int r = 0; r < 4; r++) {
                mnew[r]  = fmaxf(mrun[mt][r], mx[r]);
                alpha[r] = exp2f(mrun[mt][r] - mnew[r]);
                mrun[mt][r] = mnew[r];
            }
            float rs[4] = {0.f,0.f,0.f,0.f};
            #pragma unroll
            for (int nb = 0; nb < 4; nb++)
                for (int r = 0; r < 4; r++) {
                    const float p = exp2f(sacc[mt][nb][r] - mnew[r]);
                    rs[r] += p;
                    // XOR-swizzled P: col' = col ^ (quad<<4) -> bank-disjoint quads
                    sPw[(quad*4 + r)*LDP + ((nb*16 + ln) ^ (quad << 4))] = (f16_t)p;
                }
            #pragma unroll
            for (int r = 0; r < 4; r++) {
                rs[r] = rowsum16(rs[r]);
                lrun[mt][r] = lrun[mt][r]*alpha[r] + rs[r];
            }
            #pragma unroll
            for (int db = 0; db < 8; db++)
                for (int r = 0; r < 4; r++) oacc[mt][db][r] *= alpha[r];

            __asm__ volatile("s_waitcnt lgkmcnt(0)" ::: "memory");
            pf[mt][0] = *(const f16x8*)(sPw + ln*LDP + ((quad*8     ) ^ ((ln >> 2) << 4)));
            pf[mt][1] = *(const f16x8*)(sPw + ln*LDP + ((quad*8 + 32) ^ ((ln >> 2) << 4)));
        }

        // ---- O += P V, V fragment shared by both m-tiles ----
        #pragma unroll
        for (int db = 0; db < 8; db++) {
            #pragma unroll
            for (int ks = 0; ks < 2; ks++) {
                const f16x8 vf = *(const f16x8*)(sVt + (db*16+ln)*LDV + quad*8 + ks*32);
                oacc[0][db] = __builtin_amdgcn_mfma_f32_16x16x32_f16(pf[0][ks], vf, oacc[0][db], 0,0,0);
                oacc[1][db] = __builtin_amdgcn_mfma_f32_16x16x32_f16(pf[1][ks], vf, oacc[1][db], 0,0,0);
            }
        }
    }

    // ---- epilogue: normalize, swizzled LDS transpose, coalesced b128 stores ----
    __syncthreads();   // all compute reads of sKh/sVt done
    float inv[2][4];
    #pragma unroll
    for (int mt = 0; mt < 2; mt++)
        for (int r = 0; r < 4; r++) inv[mt][r] = 1.f / lrun[mt][r];

    f16_t* sOw = sO + wave*32*LDO;
    #pragma unroll
    for (int mt = 0; mt < 2; mt++)
        for (int db = 0; db < 8; db++)
            for (int r = 0; r < 4; r++) {
                const int row  = mt*16 + quad*4 + r;
                const int colp = (db*16 + ln) ^ (quad << 4);
                sOw[row*LDO + colp] = (f16_t)(oacc[mt][db][r] * inv[mt][r]);
            }
    __asm__ volatile("s_waitcnt lgkmcnt(0)" ::: "memory");  // wave-local round-trip

    const size_t gbase = ((size_t)sp*NROW + (size_t)b*SEQ + qrow0)*DIM;
    #pragma unroll
    for (int jj = 0; jj < 8; jj++) {
        const int c    = lane + 64*jj;
        const int row  = c >> 4;
        const int col  = (c & 15) * 8;
        const int colp = col ^ (((row >> 2) & 3) << 4);
        *(uint4*)(Opart + gbase + (size_t)row*DIM + col) =
            *(const uint4*)(sOw + row*LDO + colp);
    }
    #pragma unroll
    for (int mt = 0; mt < 2; mt++)
        for (int r = 0; r < 4; r++)
            if (ln == 0) {
                const int row = b*SEQ + qrow0 + mt*16 + quad*4 + r;
                mlbuf[sp*NROW + row] = make_float2(mrun[mt][r], lrun[mt][r]);
            }
}

// ---------------------------------------------------------------------------
// Kernel 3: combine the KV-split partials.
// ---------------------------------------------------------------------------
__global__ __launch_bounds__(256) void combine_kernel(
    const f16_t* __restrict__ Opart, const float2* __restrict__ mlbuf,
    float* __restrict__ out)
{
    const int idx = blockIdx.x*256 + threadIdx.x;
    const int row = idx >> 4;
    const int d0  = (idx & 15) * 8;

    float m[NSPLIT], l[NSPLIT];
    #pragma unroll
    for (int s = 0; s < NSPLIT; s++) {
        const float2 v = mlbuf[s*NROW + row];
        m[s] = v.x; l[s] = v.y;
    }
    float M = m[0];
    #pragma unroll
    for (int s = 1; s < NSPLIT; s++) M = fmaxf(M, m[s]);
    float w[NSPLIT], denom = 0.f;
    #pragma unroll
    for (int s = 0; s < NSPLIT; s++) { w[s] = l[s] * exp2f(m[s] - M); denom += w[s]; }
    const float inv = 1.f / denom;

    float o[8] = {0,0,0,0,0,0,0,0};
    #pragma unroll
    for (int s = 0; s < NSPLIT; s++) {
        const f16x8 v = *(const f16x8*)(Opart + ((size_t)s*NROW + row)*DIM + d0);
        const float ws = w[s] * inv;
        #pragma unroll
        for (int j = 0; j < 8; j++) o[j] += ws * (float)v[j];
    }
    float* ob = out + (size_t)row*DIM + d0;
    *(float4*)(ob)     = make_float4(o[0], o[1], o[2], o[3]);
    *(float4*)(ob + 4) = make_float4(o[4], o[5], o[6], o[7]);
}

// ---------------------------------------------------------------------------
extern "C" void kernel_launch(void* const* d_in, const int* in_sizes, int n_in,
                              void* d_out, int out_size, void* d_ws, size_t ws_size,
                              hipStream_t stream) {
    const float* x  = (const float*)d_in[0];
    // d_in[1] = token_attention_masks (unused: reference softmaxes UNMASKED scores)
    const float* wq = (const float*)d_in[2];
    const float* wk = (const float*)d_in[3];
    const float* wv = (const float*)d_in[4];

    f16_t* ws = (f16_t*)d_ws;
    f16_t* Qh    = ws;                                    // NROW*DIM each
    f16_t* Ql    = Qh  + (size_t)NROW*DIM;
    f16_t* Kh    = Ql  + (size_t)NROW*DIM;
    f16_t* Vt    = Kh  + (size_t)NROW*DIM;                // [B][D][S]
    f16_t* Wth   = Vt  + (size_t)NROW*DIM;                // NW*DIM each
    f16_t* Wtl   = Wth + (size_t)NW*DIM;
    f16_t* Opart = Wtl + (size_t)NW*DIM;                  // NSPLIT x NROW x DIM
    float2* mlbuf = (float2*)(Opart + (size_t)NSPLIT*NROW*DIM);

    wsplit_kernel <<<NW*DIM/256,        256, 0, stream>>>(wq, wk, wv, Wth, Wtl);
    proj_kernel   <<<(NROW/64)*3,       256, 0, stream>>>(x, Wth, Wtl, Qh, Ql, Kh, Vt);
    flash_kernel  <<<BATCH*32*NSPLIT,   256, 0, stream>>>(Qh, Ql, Kh, Vt, Opart, mlbuf);
    combine_kernel<<<NROW*DIM/8/256,    256, 0, stream>>>(Opart, mlbuf, (float*)d_out);
}

// Round 5
// 188.150 us; speedup vs baseline: 1.3815x; 1.0093x over previous
//
#include <hip/hip_runtime.h>
#include <math.h>

#define BATCH  4
#define SEQ    4096
#define DIM    128
#define NROW   (BATCH*SEQ)
#define NSPLIT 4
#define NW     384   // concatenated W cols (q|k|v)

typedef _Float16 f16_t;
typedef _Float16 f16x4 __attribute__((ext_vector_type(4)));
typedef _Float16 f16x8 __attribute__((ext_vector_type(8)));
typedef float    f32x4 __attribute__((ext_vector_type(4)));

// softmax scale 1/sqrt(128) and log2(e) folded into Q
#define QSCALE ((float)(1.4426950408889634 / 11.313708498984761))

// ---- DPP 16-lane-row allreduce (pure VALU) ----
template<int CTRL>
__device__ __forceinline__ float dpp_mov(float x) {
    return __builtin_bit_cast(float,
        __builtin_amdgcn_update_dpp(0, __builtin_bit_cast(int, x), CTRL, 0xF, 0xF, true));
}
__device__ __forceinline__ float rowsum16(float x) {
    x += dpp_mov<0x121>(x);
    x += dpp_mov<0x122>(x);
    x += dpp_mov<0x124>(x);
    x += dpp_mov<0x128>(x);
    return x;
}
__device__ __forceinline__ float rowmax16(float x) {
    x = fmaxf(x, dpp_mov<0x121>(x));
    x = fmaxf(x, dpp_mov<0x122>(x));
    x = fmaxf(x, dpp_mov<0x124>(x));
    x = fmaxf(x, dpp_mov<0x128>(x));
    return x;
}

// ---------------------------------------------------------------------------
// Kernel 0: transpose+hi/lo-split W once: Wt[n][k] = W[k][n] as f16 h/l.
// ---------------------------------------------------------------------------
__global__ __launch_bounds__(256) void wsplit_kernel(
    const float* __restrict__ wq, const float* __restrict__ wk,
    const float* __restrict__ wv,
    f16_t* __restrict__ Wth, f16_t* __restrict__ Wtl)
{
    const int idx = blockIdx.x*256 + threadIdx.x;   // 49152 = 384*128
    const int n = idx >> 7;
    const int k = idx & 127;
    const int mat = n >> 7, col = n & 127;
    const float* w = (mat == 0) ? wq : ((mat == 1) ? wk : wv);
    const float v = w[k*DIM + col];
    const f16_t h = (f16_t)v;
    Wth[idx] = h;
    Wtl[idx] = (f16_t)(v - (float)h);
}

// ---------------------------------------------------------------------------
// Kernel 1: QKV projection as MFMA GEMM (3-term compensated, fp32-accurate).
// Epilogue: C-layout -> swizzled LDS -> b128 coalesced global stores.
// ---------------------------------------------------------------------------
#define LDX 72    // staging stride (144B)
#define LDE 136   // epilogue transpose stride (272B)

__global__ __launch_bounds__(256) void proj_kernel(
    const float* __restrict__ x,
    const f16_t* __restrict__ Wth, const f16_t* __restrict__ Wtl,
    f16_t* __restrict__ Qh, f16_t* __restrict__ Ql,
    f16_t* __restrict__ Kh, f16_t* __restrict__ Vt)
{
    __shared__ __align__(16) f16_t smem[(64 + 64 + 128 + 128) * LDX]; // 55296 B
    f16_t* sXh = smem;
    f16_t* sXl = smem + 64*LDX;
    f16_t* sWh = smem + 128*LDX;
    f16_t* sWl = smem + 256*LDX;

    const int tid  = threadIdx.x;
    const int wave = tid >> 6;
    const int lane = tid & 63;
    const int quad = lane >> 4;
    const int ln   = lane & 15;

    const int nt = blockIdx.x % 3;          // 0=Q 1=K 2=V
    const int mb = blockIdx.x / 3;
    const int m0 = mb * 64;
    const int n0 = nt * 128;

    f32x4 acc[8];
    #pragma unroll
    for (int nb = 0; nb < 8; nb++)
        for (int r = 0; r < 4; r++) acc[nb][r] = 0.f;

    #pragma unroll
    for (int ph = 0; ph < 2; ph++) {
        __syncthreads();
        #pragma unroll
        for (int i = 0; i < 4; i++) {
            const int idx = tid + 256*i;
            const int r = idx >> 4, f4 = idx & 15;
            const float4 v = *(const float4*)(x + (size_t)(m0+r)*DIM + ph*64 + f4*4);
            f16_t h0=(f16_t)v.x, h1=(f16_t)v.y, h2=(f16_t)v.z, h3=(f16_t)v.w;
            *(f16x4*)(sXh + r*LDX + f4*4) = (f16x4){h0,h1,h2,h3};
            *(f16x4*)(sXl + r*LDX + f4*4) =
                (f16x4){(f16_t)(v.x-(float)h0),(f16_t)(v.y-(float)h1),
                        (f16_t)(v.z-(float)h2),(f16_t)(v.w-(float)h3)};
        }
        #pragma unroll
        for (int i = 0; i < 4; i++) {
            const int idx = tid + 256*i;
            const int n = idx >> 3, g = idx & 7;
            *(uint4*)(sWh + n*LDX + g*8) =
                *(const uint4*)(Wth + (size_t)(n0+n)*DIM + ph*64 + g*8);
            *(uint4*)(sWl + n*LDX + g*8) =
                *(const uint4*)(Wtl + (size_t)(n0+n)*DIM + ph*64 + g*8);
        }
        __syncthreads();

        f16x8 ah[2], al[2];
        #pragma unroll
        for (int ks = 0; ks < 2; ks++) {
            ah[ks] = *(const f16x8*)(sXh + (wave*16+ln)*LDX + quad*8 + ks*32);
            al[ks] = *(const f16x8*)(sXl + (wave*16+ln)*LDX + quad*8 + ks*32);
        }
        #pragma unroll
        for (int nb = 0; nb < 8; nb++) {
            #pragma unroll
            for (int ks = 0; ks < 2; ks++) {
                const f16x8 bh = *(const f16x8*)(sWh + (nb*16+ln)*LDX + quad*8 + ks*32);
                const f16x8 bl = *(const f16x8*)(sWl + (nb*16+ln)*LDX + quad*8 + ks*32);
                acc[nb] = __builtin_amdgcn_mfma_f32_16x16x32_f16(ah[ks], bh, acc[nb], 0,0,0);
                acc[nb] = __builtin_amdgcn_mfma_f32_16x16x32_f16(al[ks], bh, acc[nb], 0,0,0);
                acc[nb] = __builtin_amdgcn_mfma_f32_16x16x32_f16(ah[ks], bl, acc[nb], 0,0,0);
            }
        }
    }

    __syncthreads();   // done with staging LDS

    if (nt != 2) {
        // ---- Q/K epilogue: swizzled LDS transpose -> coalesced b128 stores ----
        const float scale = (nt == 0) ? QSCALE : 1.0f;
        f16_t* dsth = (nt == 0) ? Qh : Kh;
        f16_t* sH = smem;             // 64 x LDE
        f16_t* sL = smem + 64*LDE;    // 64 x LDE
        #pragma unroll
        for (int nb = 0; nb < 8; nb++)
            #pragma unroll
            for (int r = 0; r < 4; r++) {
                const int row  = wave*16 + quad*4 + r;
                const int colp = (nb*16 + ln) ^ (quad << 4);
                const float v  = acc[nb][r] * scale;
                const f16_t h  = (f16_t)v;
                sH[row*LDE + colp] = h;
                if (nt == 0) sL[row*LDE + colp] = (f16_t)(v - (float)h);
            }
        __syncthreads();
        #pragma unroll
        for (int jj = 0; jj < 4; jj++) {
            const int c    = tid + 256*jj;
            const int row  = c >> 4;
            const int col  = (c & 15) * 8;
            const int colp = col ^ (((row >> 2) & 3) << 4);
            const size_t g = (size_t)(m0 + row)*DIM + col;
            *(uint4*)(dsth + g) = *(const uint4*)(sH + row*LDE + colp);
            if (nt == 0)
                *(uint4*)(Ql + g) = *(const uint4*)(sL + row*LDE + colp);
        }
    } else {
        // ---- V epilogue: transpose to Vt[b][d][s] ----
        f16_t* svt = smem;                  // 128 x LDX, [d][s_local]
        const int rowl = wave*16 + quad*4;
        #pragma unroll
        for (int nb = 0; nb < 8; nb++)
            for (int r = 0; r < 4; r++)
                svt[(nb*16+ln)*LDX + rowl + r] = (f16_t)acc[nb][r];
        __syncthreads();
        const int bb = m0 >> 12, sloc = m0 & (SEQ-1);
        const int d = tid >> 1, half = tid & 1;
        #pragma unroll
        for (int q = 0; q < 4; q++) {
            *(uint4*)(Vt + ((size_t)bb*DIM + d)*SEQ + sloc + half*32 + q*8) =
                *(const uint4*)(svt + d*LDX + half*32 + q*8);
        }
    }
}

// ---------------------------------------------------------------------------
// Kernel 2: fused flash attention. 512-thread blocks (8 waves x 16 Q rows =
// 128 rows/block), KV-split=4. __launch_bounds__(512,4) -> 4 waves/SIMD
// (2 blocks/CU) for latency hiding; LDS 54.3 KB/block. 2-term compensated
// QK^T (Q*Kh). XCD-aware block mapping: all 32 qt-blocks of one (b,sp)
// K/V slice (512 KB, L2-resident) land on one XCD.
// ---------------------------------------------------------------------------
#define LDK 136
#define LDV 72
#define LDP 72
#define LDO 136

__global__ __launch_bounds__(512, 4) void flash_kernel(
    const f16_t* __restrict__ Qh, const f16_t* __restrict__ Ql,
    const f16_t* __restrict__ Kh, const f16_t* __restrict__ Vt,
    f16_t* __restrict__ Opart, float2* __restrict__ mlbuf)
{
    __shared__ __align__(16) f16_t smem[64*LDK + 128*LDV + 8*16*LDP]; // 54272 B
    f16_t* sKh = smem;
    f16_t* sVt = smem + 64*LDK;
    f16_t* sP  = smem + 64*LDK + 128*LDV;
    f16_t* sO  = smem;   // epilogue reuse: 8 waves x 16 x LDO = 34816 B

    const int tid  = threadIdx.x;
    const int wave = tid >> 6;
    const int lane = tid & 63;
    const int quad = lane >> 4;
    const int ln   = lane & 15;

    // XCD-aware mapping: group = (b,sp) fixed per XCD-slot, qt varies
    const int grp = blockIdx.x & 15;    // b*4 + sp
    const int b   = grp >> 2;
    const int sp  = grp & 3;
    const int qt  = blockIdx.x >> 4;    // 0..31
    const int qrow0 = qt*128 + wave*16;

    f16x8 qhf[4], qlf[4];
    {
        const size_t gq = ((size_t)b*SEQ + qrow0 + ln)*DIM;
        #pragma unroll
        for (int ks = 0; ks < 4; ks++) {
            qhf[ks] = *(const f16x8*)(Qh + gq + quad*8 + ks*32);
            qlf[ks] = *(const f16x8*)(Ql + gq + quad*8 + ks*32);
        }
    }

    f32x4 oacc[8];
    #pragma unroll
    for (int db = 0; db < 8; db++)
        for (int r = 0; r < 4; r++) oacc[db][r] = 0.f;
    float mrun[4], lrun[4];
    #pragma unroll
    for (int r = 0; r < 4; r++) { mrun[r] = -__builtin_inff(); lrun[r] = 0.f; }

    f16_t* sPw = sP + wave*16*LDP;

    // staging chunk coordinates (512 threads: 2 chunks each for K and V)
    const int kr[2] = { tid >> 4, (tid + 512) >> 4 };
    const int kc    = (tid & 15) * 8;
    const int vd[2] = { tid >> 3, (tid + 512) >> 3 };
    const int vj    = (tid & 7) * 8;

    const f16_t* gKbase = Kh + (size_t)b*SEQ*DIM;
    const f16_t* gVbase = Vt + (size_t)b*DIM*SEQ;

    const int kt0 = sp*16, kend = sp*16 + 16;

    for (int kt = kt0; kt < kend; kt++) {
        // issue global loads BEFORE the barrier (regs only; prev-tile LDS
        // reads by THIS wave are already done) -> latency overlaps the
        // barrier wait and other waves' compute tails
        float4 pk[2], pv[2];
        {
            const f16_t* gk = gKbase + (size_t)kt*64*DIM;
            const f16_t* gv = gVbase + kt*64;
            #pragma unroll
            for (int p = 0; p < 2; p++) pk[p] = *(const float4*)(gk + kr[p]*DIM + kc);
            #pragma unroll
            for (int p = 0; p < 2; p++) pv[p] = *(const float4*)(gv + (size_t)vd[p]*SEQ + vj);
        }
        __syncthreads();   // all waves done reading previous tile
        #pragma unroll
        for (int p = 0; p < 2; p++) *(float4*)(sKh + kr[p]*LDK + kc) = pk[p];
        #pragma unroll
        for (int p = 0; p < 2; p++) *(float4*)(sVt + vd[p]*LDV + vj) = pv[p];
        __syncthreads();

        // ---- S = Q K^T (2-term: (Qh+Ql)*Kh) ----
        f32x4 sacc[4];
        #pragma unroll
        for (int nb = 0; nb < 4; nb++)
            for (int r = 0; r < 4; r++) sacc[nb][r] = 0.f;
        #pragma unroll
        for (int ks = 0; ks < 4; ks++) {
            #pragma unroll
            for (int nb = 0; nb < 4; nb++) {
                const f16x8 khf = *(const f16x8*)(sKh + (nb*16+ln)*LDK + quad*8 + ks*32);
                sacc[nb] = __builtin_amdgcn_mfma_f32_16x16x32_f16(qhf[ks], khf, sacc[nb], 0,0,0);
                sacc[nb] = __builtin_amdgcn_mfma_f32_16x16x32_f16(qlf[ks], khf, sacc[nb], 0,0,0);
            }
        }

        // ---- online softmax ----
        float mx[4];
        #pragma unroll
        for (int r = 0; r < 4; r++) {
            mx[r] = fmaxf(fmaxf(sacc[0][r], sacc[1][r]),
                          fmaxf(sacc[2][r], sacc[3][r]));
            mx[r] = rowmax16(mx[r]);
        }
        float alpha[4], mnew[4];
        #pragma unroll
        for (int r = 0; r < 4; r++) {
            mnew[r]  = fmaxf(mrun[r], mx[r]);
            alpha[r] = exp2f(mrun[r] - mnew[r]);
            mrun[r]  = mnew[r];
        }
        float rs[4] = {0.f,0.f,0.f,0.f};
        #pragma unroll
        for (int nb = 0; nb < 4; nb++)
            for (int r = 0; r < 4; r++) {
                const float p = exp2f(sacc[nb][r] - mnew[r]);
                rs[r] += p;
                // XOR-swizzled P: col' = col ^ (quad<<4)
                sPw[(quad*4 + r)*LDP + ((nb*16 + ln) ^ (quad << 4))] = (f16_t)p;
            }
        #pragma unroll
        for (int r = 0; r < 4; r++) {
            rs[r] = rowsum16(rs[r]);
            lrun[r] = lrun[r]*alpha[r] + rs[r];
        }
        #pragma unroll
        for (int db = 0; db < 8; db++)
            for (int r = 0; r < 4; r++) oacc[db][r] *= alpha[r];

        // wave-local P round-trip (DS ops in-order per wave)
        __asm__ volatile("s_waitcnt lgkmcnt(0)" ::: "memory");
        f16x8 pf[2];
        pf[0] = *(const f16x8*)(sPw + ln*LDP + ((quad*8     ) ^ ((ln >> 2) << 4)));
        pf[1] = *(const f16x8*)(sPw + ln*LDP + ((quad*8 + 32) ^ ((ln >> 2) << 4)));

        // ---- O += P V ----
        #pragma unroll
        for (int db = 0; db < 8; db++) {
            #pragma unroll
            for (int ks = 0; ks < 2; ks++) {
                const f16x8 vf = *(const f16x8*)(sVt + (db*16+ln)*LDV + quad*8 + ks*32);
                oacc[db] = __builtin_amdgcn_mfma_f32_16x16x32_f16(pf[ks], vf, oacc[db], 0,0,0);
            }
        }
    }

    // ---- epilogue: normalize, swizzled LDS transpose, coalesced b128 stores ----
    __syncthreads();   // all compute reads of sKh/sVt done
    float inv[4];
    #pragma unroll
    for (int r = 0; r < 4; r++) inv[r] = 1.f / lrun[r];

    f16_t* sOw = sO + wave*16*LDO;
    #pragma unroll
    for (int db = 0; db < 8; db++)
        for (int r = 0; r < 4; r++) {
            const int row  = quad*4 + r;
            const int colp = (db*16 + ln) ^ (quad << 4);
            sOw[row*LDO + colp] = (f16_t)(oacc[db][r] * inv[r]);
        }
    __asm__ volatile("s_waitcnt lgkmcnt(0)" ::: "memory");  // wave-local round-trip

    const size_t gbase = ((size_t)sp*NROW + (size_t)b*SEQ + qrow0)*DIM;
    #pragma unroll
    for (int jj = 0; jj < 4; jj++) {
        const int c    = lane + 64*jj;
        const int row  = c >> 4;
        const int col  = (c & 15) * 8;
        const int colp = col ^ (((row >> 2) & 3) << 4);
        *(uint4*)(Opart + gbase + (size_t)row*DIM + col) =
            *(const uint4*)(sOw + row*LDO + colp);
    }
    if (ln == 0) {
        #pragma unroll
        for (int r = 0; r < 4; r++) {
            const int row = b*SEQ + qrow0 + quad*4 + r;
            mlbuf[sp*NROW + row] = make_float2(mrun[r], lrun[r]);
        }
    }
}

// ---------------------------------------------------------------------------
// Kernel 3: combine the KV-split partials.
// ---------------------------------------------------------------------------
__global__ __launch_bounds__(256) void combine_kernel(
    const f16_t* __restrict__ Opart, const float2* __restrict__ mlbuf,
    float* __restrict__ out)
{
    const int idx = blockIdx.x*256 + threadIdx.x;
    const int row = idx >> 4;
    const int d0  = (idx & 15) * 8;

    float m[NSPLIT], l[NSPLIT];
    #pragma unroll
    for (int s = 0; s < NSPLIT; s++) {
        const float2 v = mlbuf[s*NROW + row];
        m[s] = v.x; l[s] = v.y;
    }
    float M = m[0];
    #pragma unroll
    for (int s = 1; s < NSPLIT; s++) M = fmaxf(M, m[s]);
    float w[NSPLIT], denom = 0.f;
    #pragma unroll
    for (int s = 0; s < NSPLIT; s++) { w[s] = l[s] * exp2f(m[s] - M); denom += w[s]; }
    const float inv = 1.f / denom;

    float o[8] = {0,0,0,0,0,0,0,0};
    #pragma unroll
    for (int s = 0; s < NSPLIT; s++) {
        const f16x8 v = *(const f16x8*)(Opart + ((size_t)s*NROW + row)*DIM + d0);
        const float ws = w[s] * inv;
        #pragma unroll
        for (int j = 0; j < 8; j++) o[j] += ws * (float)v[j];
    }
    float* ob = out + (size_t)row*DIM + d0;
    *(float4*)(ob)     = make_float4(o[0], o[1], o[2], o[3]);
    *(float4*)(ob + 4) = make_float4(o[4], o[5], o[6], o[7]);
}

// ---------------------------------------------------------------------------
extern "C" void kernel_launch(void* const* d_in, const int* in_sizes, int n_in,
                              void* d_out, int out_size, void* d_ws, size_t ws_size,
                              hipStream_t stream) {
    const float* x  = (const float*)d_in[0];
    // d_in[1] = token_attention_masks (unused: reference softmaxes UNMASKED scores)
    const float* wq = (const float*)d_in[2];
    const float* wk = (const float*)d_in[3];
    const float* wv = (const float*)d_in[4];

    f16_t* ws = (f16_t*)d_ws;
    f16_t* Qh    = ws;                                    // NROW*DIM each
    f16_t* Ql    = Qh  + (size_t)NROW*DIM;
    f16_t* Kh    = Ql  + (size_t)NROW*DIM;
    f16_t* Vt    = Kh  + (size_t)NROW*DIM;                // [B][D][S]
    f16_t* Wth   = Vt  + (size_t)NROW*DIM;                // NW*DIM each
    f16_t* Wtl   = Wth + (size_t)NW*DIM;
    f16_t* Opart = Wtl + (size_t)NW*DIM;                  // NSPLIT x NROW x DIM
    float2* mlbuf = (float2*)(Opart + (size_t)NSPLIT*NROW*DIM);

    wsplit_kernel <<<NW*DIM/256,        256, 0, stream>>>(wq, wk, wv, Wth, Wtl);
    proj_kernel   <<<(NROW/64)*3,       256, 0, stream>>>(x, Wth, Wtl, Qh, Ql, Kh, Vt);
    flash_kernel  <<<BATCH*32*NSPLIT,   512, 0, stream>>>(Qh, Ql, Kh, Vt, Opart, mlbuf);
    combine_kernel<<<NROW*DIM/8/256,    256, 0, stream>>>(Opart, mlbuf, (float*)d_out);
}

// Round 7
// 132.390 us; speedup vs baseline: 1.9633x; 1.4212x over previous
//
#include <hip/hip_runtime.h>
#include <math.h>

#define BATCH  4
#define SEQ    4096
#define DIM    128
#define NROW   (BATCH*SEQ)
#define NSPLIT 8
#define NW     384   // concatenated W cols (q|k|v)

typedef _Float16 f16_t;
typedef _Float16 f16x4  __attribute__((ext_vector_type(4)));
typedef _Float16 f16x8  __attribute__((ext_vector_type(8)));
typedef _Float16 f16x16 __attribute__((ext_vector_type(16)));
typedef float    f32x4  __attribute__((ext_vector_type(4)));
typedef float    f32x16 __attribute__((ext_vector_type(16)));

// softmax scale 1/sqrt(128) and log2(e) folded into Q
#define QSCALE ((float)(1.4426950408889634 / 11.313708498984761))

// ---------------------------------------------------------------------------
// Kernel 0: transpose+hi/lo-split W once: Wt[n][k] = W[k][n] as f16 h/l.
// (proj GEMM stays 3-term compensated so Q/K/V are fp32-accurate pre-round)
// ---------------------------------------------------------------------------
__global__ __launch_bounds__(256) void wsplit_kernel(
    const float* __restrict__ wq, const float* __restrict__ wk,
    const float* __restrict__ wv,
    f16_t* __restrict__ Wth, f16_t* __restrict__ Wtl)
{
    const int idx = blockIdx.x*256 + threadIdx.x;   // 49152 = 384*128
    const int n = idx >> 7;
    const int k = idx & 127;
    const int mat = n >> 7, col = n & 127;
    const float* w = (mat == 0) ? wq : ((mat == 1) ? wk : wv);
    const float v = w[k*DIM + col];
    const f16_t h = (f16_t)v;
    Wth[idx] = h;
    Wtl[idx] = (f16_t)(v - (float)h);
}

// ---------------------------------------------------------------------------
// Kernel 1: QKV projection as MFMA GEMM (3-term compensated, fp32-accurate).
// Outputs: Qh (scaled f16), Kh (f16), Vt[b][d][s] (f16).
// ---------------------------------------------------------------------------
#define LDX 72    // staging stride (144B)
#define LDE 136   // epilogue transpose stride (272B)

__global__ __launch_bounds__(256) void proj_kernel(
    const float* __restrict__ x,
    const f16_t* __restrict__ Wth, const f16_t* __restrict__ Wtl,
    f16_t* __restrict__ Qh, f16_t* __restrict__ Kh, f16_t* __restrict__ Vt)
{
    __shared__ __align__(16) f16_t smem[(64 + 64 + 128 + 128) * LDX]; // 55296 B
    f16_t* sXh = smem;
    f16_t* sXl = smem + 64*LDX;
    f16_t* sWh = smem + 128*LDX;
    f16_t* sWl = smem + 256*LDX;

    const int tid  = threadIdx.x;
    const int wave = tid >> 6;
    const int lane = tid & 63;
    const int quad = lane >> 4;
    const int ln   = lane & 15;

    const int nt = blockIdx.x % 3;          // 0=Q 1=K 2=V
    const int mb = blockIdx.x / 3;
    const int m0 = mb * 64;
    const int n0 = nt * 128;

    f32x4 acc[8];
    #pragma unroll
    for (int nb = 0; nb < 8; nb++)
        for (int r = 0; r < 4; r++) acc[nb][r] = 0.f;

    #pragma unroll
    for (int ph = 0; ph < 2; ph++) {
        __syncthreads();
        #pragma unroll
        for (int i = 0; i < 4; i++) {
            const int idx = tid + 256*i;
            const int r = idx >> 4, f4 = idx & 15;
            const float4 v = *(const float4*)(x + (size_t)(m0+r)*DIM + ph*64 + f4*4);
            f16_t h0=(f16_t)v.x, h1=(f16_t)v.y, h2=(f16_t)v.z, h3=(f16_t)v.w;
            *(f16x4*)(sXh + r*LDX + f4*4) = (f16x4){h0,h1,h2,h3};
            *(f16x4*)(sXl + r*LDX + f4*4) =
                (f16x4){(f16_t)(v.x-(float)h0),(f16_t)(v.y-(float)h1),
                        (f16_t)(v.z-(float)h2),(f16_t)(v.w-(float)h3)};
        }
        #pragma unroll
        for (int i = 0; i < 4; i++) {
            const int idx = tid + 256*i;
            const int n = idx >> 3, g = idx & 7;
            *(uint4*)(sWh + n*LDX + g*8) =
                *(const uint4*)(Wth + (size_t)(n0+n)*DIM + ph*64 + g*8);
            *(uint4*)(sWl + n*LDX + g*8) =
                *(const uint4*)(Wtl + (size_t)(n0+n)*DIM + ph*64 + g*8);
        }
        __syncthreads();

        f16x8 ah[2], al[2];
        #pragma unroll
        for (int ks = 0; ks < 2; ks++) {
            ah[ks] = *(const f16x8*)(sXh + (wave*16+ln)*LDX + quad*8 + ks*32);
            al[ks] = *(const f16x8*)(sXl + (wave*16+ln)*LDX + quad*8 + ks*32);
        }
        #pragma unroll
        for (int nb = 0; nb < 8; nb++) {
            #pragma unroll
            for (int ks = 0; ks < 2; ks++) {
                const f16x8 bh = *(const f16x8*)(sWh + (nb*16+ln)*LDX + quad*8 + ks*32);
                const f16x8 bl = *(const f16x8*)(sWl + (nb*16+ln)*LDX + quad*8 + ks*32);
                acc[nb] = __builtin_amdgcn_mfma_f32_16x16x32_f16(ah[ks], bh, acc[nb], 0,0,0);
                acc[nb] = __builtin_amdgcn_mfma_f32_16x16x32_f16(al[ks], bh, acc[nb], 0,0,0);
                acc[nb] = __builtin_amdgcn_mfma_f32_16x16x32_f16(ah[ks], bl, acc[nb], 0,0,0);
            }
        }
    }

    __syncthreads();   // done with staging LDS

    if (nt != 2) {
        // ---- Q/K epilogue: swizzled LDS transpose -> coalesced b128 stores ----
        const float scale = (nt == 0) ? QSCALE : 1.0f;
        f16_t* dsth = (nt == 0) ? Qh : Kh;
        f16_t* sH = smem;             // 64 x LDE
        #pragma unroll
        for (int nb = 0; nb < 8; nb++)
            #pragma unroll
            for (int r = 0; r < 4; r++) {
                const int row  = wave*16 + quad*4 + r;
                const int colp = (nb*16 + ln) ^ (quad << 4);
                sH[row*LDE + colp] = (f16_t)(acc[nb][r] * scale);
            }
        __syncthreads();
        #pragma unroll
        for (int jj = 0; jj < 4; jj++) {
            const int c    = tid + 256*jj;
            const int row  = c >> 4;
            const int col  = (c & 15) * 8;
            const int colp = col ^ (((row >> 2) & 3) << 4);
            *(uint4*)(dsth + (size_t)(m0 + row)*DIM + col) =
                *(const uint4*)(sH + row*LDE + colp);
        }
    } else {
        // ---- V epilogue: transpose to Vt[b][d][s] ----
        f16_t* svt = smem;                  // 128 x LDX, [d][s_local]
        const int rowl = wave*16 + quad*4;
        #pragma unroll
        for (int nb = 0; nb < 8; nb++)
            for (int r = 0; r < 4; r++)
                svt[(nb*16+ln)*LDX + rowl + r] = (f16_t)acc[nb][r];
        __syncthreads();
        const int bb = m0 >> 12, sloc = m0 & (SEQ-1);
        const int d = tid >> 1, half = tid & 1;
        #pragma unroll
        for (int q = 0; q < 4; q++) {
            *(uint4*)(Vt + ((size_t)bb*DIM + d)*SEQ + sloc + half*32 + q*8) =
                *(const uint4*)(svt + d*LDX + half*32 + q*8);
        }
    }
}

// ---------------------------------------------------------------------------
// Kernel 2: fused flash attention, S^T formulation on 32x32x16 MFMA.
//   S^T = K Q^T  (A = K from LDS, B = Q in regs; 32 q-rows/wave)
//   O^T = V^T P^T (A = V^T from LDS; B = P^T comes STRAIGHT from S^T's
//   accumulator registers via the k-mapping s = 4h + (j&3) + 8(j>>2) applied
//   consistently to both operands -> no LDS round-trip, no shuffles for P).
// 256-thr blocks (4 waves x 32 q = 128 q/block), NSPLIT=8 -> grid 1024,
// LDS 34.3 KB, __launch_bounds__(256,3) -> 12 waves/CU.
// All K/V LDS access is b64 with LDK=132 / LDV=68 (~2-4-way bank = cheap).
// ---------------------------------------------------------------------------
#define LDK 132
#define LDV 68
#define LDO 132

__global__ __launch_bounds__(256, 3) void flash_kernel(
    const f16_t* __restrict__ Qh, const f16_t* __restrict__ Kh,
    const f16_t* __restrict__ Vt,
    f16_t* __restrict__ Opart, float2* __restrict__ mlbuf)
{
    __shared__ __align__(16) f16_t smem[64*LDK + 128*LDV]; // 34304 B
    f16_t* sK = smem;
    f16_t* sV = smem + 64*LDK;

    const int tid  = threadIdx.x;
    const int wave = tid >> 6;
    const int lane = tid & 63;
    const int l31  = lane & 31;
    const int h    = lane >> 5;

    const int grp = blockIdx.x & 31;          // (b, sp) -> XCD-local K/V slice
    const int b   = grp >> 3;
    const int sp  = grp & 7;
    const int qt  = blockIdx.x >> 5;          // 0..31
    const int q0  = qt*128 + wave*32;

    // Q B-frags: lane holds Q[q = q0+l31][d = ks*16 + h*8 + j], j=0..7
    f16x8 qf[8];
    {
        const f16_t* gq = Qh + ((size_t)b*SEQ + q0 + l31)*DIM + h*8;
        #pragma unroll
        for (int ks = 0; ks < 8; ks++)
            qf[ks] = *(const f16x8*)(gq + ks*16);
    }

    f32x16 oacc[4];
    #pragma unroll
    for (int mb = 0; mb < 4; mb++)
        #pragma unroll
        for (int r = 0; r < 16; r++) oacc[mb][r] = 0.f;
    float mrun = -__builtin_inff(), lrun = 0.f;

    // staging coords (K: 64x128 tile; V: 128x64 tile; 4 float4/thread each)
    const int kr = tid >> 4;
    const int kc = (tid & 15) * 8;
    const int vd = tid >> 3;
    const int vj = (tid & 7) * 8;

    const f16_t* gK = Kh + (size_t)b*SEQ*DIM;
    const f16_t* gV = Vt + (size_t)b*DIM*SEQ;

    for (int kt = sp*8; kt < sp*8 + 8; kt++) {
        float4 pk[4], pv[4];
        {   // issue global loads before the barrier (latency overlap)
            const f16_t* gk = gK + (size_t)kt*64*DIM;
            const f16_t* gv = gV + kt*64;
            #pragma unroll
            for (int p = 0; p < 4; p++)
                pk[p] = *(const float4*)(gk + (kr + 16*p)*DIM + kc);
            #pragma unroll
            for (int p = 0; p < 4; p++)
                pv[p] = *(const float4*)(gv + (size_t)(vd + 32*p)*SEQ + vj);
        }
        __syncthreads();   // all waves done reading previous tile
        #pragma unroll
        for (int p = 0; p < 4; p++) {   // 2x b64 per chunk (odd rows not 16B-aligned)
            const f16x8 w = __builtin_bit_cast(f16x8, pk[p]);
            *(f16x4*)(sK + (kr+16*p)*LDK + kc    ) = __builtin_shufflevector(w, w, 0,1,2,3);
            *(f16x4*)(sK + (kr+16*p)*LDK + kc + 4) = __builtin_shufflevector(w, w, 4,5,6,7);
        }
        #pragma unroll
        for (int p = 0; p < 4; p++) {
            const f16x8 w = __builtin_bit_cast(f16x8, pv[p]);
            *(f16x4*)(sV + (vd+32*p)*LDV + vj    ) = __builtin_shufflevector(w, w, 0,1,2,3);
            *(f16x4*)(sV + (vd+32*p)*LDV + vj + 4) = __builtin_shufflevector(w, w, 4,5,6,7);
        }
        __syncthreads();

        // ---- S^T = K Q^T : 2 s-blocks x 8 k-steps ----
        f32x16 sacc[2];
        #pragma unroll
        for (int sb = 0; sb < 2; sb++)
            #pragma unroll
            for (int r = 0; r < 16; r++) sacc[sb][r] = 0.f;
        #pragma unroll
        for (int ks = 0; ks < 8; ks++) {
            #pragma unroll
            for (int sb = 0; sb < 2; sb++) {
                const f16_t* ka = sK + (sb*32 + l31)*LDK + ks*16 + h*8;
                const f16x4 a0 = *(const f16x4*)(ka);
                const f16x4 a1 = *(const f16x4*)(ka + 4);
                const f16x8 af = __builtin_shufflevector(a0, a1, 0,1,2,3,4,5,6,7);
                sacc[sb] = __builtin_amdgcn_mfma_f32_32x32x16_f16(af, qf[ks], sacc[sb], 0,0,0);
            }
        }

        // ---- online softmax: per-lane state (q = l31), one xor32 each ----
        float mx = sacc[0][0];
        #pragma unroll
        for (int sb = 0; sb < 2; sb++)
            #pragma unroll
            for (int r = 0; r < 16; r++) mx = fmaxf(mx, sacc[sb][r]);
        mx = fmaxf(mx, __shfl_xor(mx, 32, 64));
        const float mnew  = fmaxf(mrun, mx);
        const float alpha = exp2f(mrun - mnew);
        mrun = mnew;

        f16x16 pcv[2];
        float rs = 0.f;
        #pragma unroll
        for (int sb = 0; sb < 2; sb++)
            #pragma unroll
            for (int r = 0; r < 16; r++) {
                const float e = exp2f(sacc[sb][r] - mnew);
                rs += e;
                pcv[sb][r] = (f16_t)e;
            }
        rs += __shfl_xor(rs, 32, 64);
        lrun = lrun*alpha + rs;
        #pragma unroll
        for (int mb = 0; mb < 4; mb++)
            #pragma unroll
            for (int r = 0; r < 16; r++) oacc[mb][r] *= alpha;

        // ---- O^T += V^T P^T : P B-frag = sacc regs directly ----
        #pragma unroll
        for (int t = 0; t < 4; t++) {
            const f16x16 ps = pcv[t>>1];
            const f16x8 pb = (t & 1)
                ? __builtin_shufflevector(ps, ps, 8,9,10,11,12,13,14,15)
                : __builtin_shufflevector(ps, ps, 0,1,2,3,4,5,6,7);
            #pragma unroll
            for (int mb = 0; mb < 4; mb++) {
                const f16_t* va = sV + (mb*32 + l31)*LDV + t*16 + h*4;
                const f16x4 a0 = *(const f16x4*)(va);
                const f16x4 a1 = *(const f16x4*)(va + 8);
                const f16x8 af = __builtin_shufflevector(a0, a1, 0,1,2,3,4,5,6,7);
                oacc[mb] = __builtin_amdgcn_mfma_f32_32x32x16_f16(af, pb, oacc[mb], 0,0,0);
            }
        }
    }

    // ---- epilogue: O^T -> LDS transpose (wave-local) -> coalesced stores ----
    __syncthreads();   // other waves done reading sK/sV
    const float invl = 1.f / lrun;
    f16_t* sOw = smem + wave*32*LDO;   // 32 q-rows x 128 d
    #pragma unroll
    for (int mb = 0; mb < 4; mb++)
        #pragma unroll
        for (int rp = 0; rp < 8; rp++) {
            const int r0 = rp*2;
            const int d  = mb*32 + (r0 & 3) + 8*(r0 >> 2) + 4*h;
            union { f16_t f[2]; unsigned u; } pkv;
            pkv.f[0] = (f16_t)(oacc[mb][r0]   * invl);
            pkv.f[1] = (f16_t)(oacc[mb][r0+1] * invl);
            *(unsigned*)(sOw + l31*LDO + d) = pkv.u;
        }
    __asm__ volatile("s_waitcnt lgkmcnt(0)" ::: "memory");  // wave-local round-trip

    const size_t gb = ((size_t)sp*NROW + (size_t)b*SEQ + q0)*DIM;
    #pragma unroll
    for (int jj = 0; jj < 8; jj++) {
        const int c  = lane + 64*jj;
        const int q  = c >> 4;
        const int dc = (c & 15)*8;
        union { f16x4 v[2]; uint4 u; } o;
        o.v[0] = *(const f16x4*)(sOw + q*LDO + dc);
        o.v[1] = *(const f16x4*)(sOw + q*LDO + dc + 4);
        *(uint4*)(Opart + gb + (size_t)q*DIM + dc) = o.u;
    }
    if (h == 0)
        mlbuf[sp*NROW + b*SEQ + q0 + l31] = make_float2(mrun, lrun);
}

// ---------------------------------------------------------------------------
// Kernel 3: combine the KV-split partials.
// ---------------------------------------------------------------------------
__global__ __launch_bounds__(256) void combine_kernel(
    const f16_t* __restrict__ Opart, const float2* __restrict__ mlbuf,
    float* __restrict__ out)
{
    const int idx = blockIdx.x*256 + threadIdx.x;
    const int row = idx >> 4;
    const int d0  = (idx & 15) * 8;

    float m[NSPLIT], l[NSPLIT];
    #pragma unroll
    for (int s = 0; s < NSPLIT; s++) {
        const float2 v = mlbuf[s*NROW + row];
        m[s] = v.x; l[s] = v.y;
    }
    float M = m[0];
    #pragma unroll
    for (int s = 1; s < NSPLIT; s++) M = fmaxf(M, m[s]);
    float w[NSPLIT], denom = 0.f;
    #pragma unroll
    for (int s = 0; s < NSPLIT; s++) { w[s] = l[s] * exp2f(m[s] - M); denom += w[s]; }
    const float inv = 1.f / denom;

    float o[8] = {0,0,0,0,0,0,0,0};
    #pragma unroll
    for (int s = 0; s < NSPLIT; s++) {
        const f16x8 v = *(const f16x8*)(Opart + ((size_t)s*NROW + row)*DIM + d0);
        const float ws = w[s] * inv;
        #pragma unroll
        for (int j = 0; j < 8; j++) o[j] += ws * (float)v[j];
    }
    float* ob = out + (size_t)row*DIM + d0;
    *(float4*)(ob)     = make_float4(o[0], o[1], o[2], o[3]);
    *(float4*)(ob + 4) = make_float4(o[4], o[5], o[6], o[7]);
}

// ---------------------------------------------------------------------------
extern "C" void kernel_launch(void* const* d_in, const int* in_sizes, int n_in,
                              void* d_out, int out_size, void* d_ws, size_t ws_size,
                              hipStream_t stream) {
    const float* x  = (const float*)d_in[0];
    // d_in[1] = token_attention_masks (unused: reference softmaxes UNMASKED scores)
    const float* wq = (const float*)d_in[2];
    const float* wk = (const float*)d_in[3];
    const float* wv = (const float*)d_in[4];

    f16_t* ws = (f16_t*)d_ws;
    f16_t* Qh    = ws;                                    // NROW*DIM each
    f16_t* Kh    = Qh  + (size_t)NROW*DIM;
    f16_t* Vt    = Kh  + (size_t)NROW*DIM;                // [B][D][S]
    f16_t* Wth   = Vt  + (size_t)NROW*DIM;                // NW*DIM each
    f16_t* Wtl   = Wth + (size_t)NW*DIM;
    f16_t* Opart = Wtl + (size_t)NW*DIM;                  // NSPLIT x NROW x DIM
    float2* mlbuf = (float2*)(Opart + (size_t)NSPLIT*NROW*DIM);

    wsplit_kernel <<<NW*DIM/256,            256, 0, stream>>>(wq, wk, wv, Wth, Wtl);
    proj_kernel   <<<(NROW/64)*3,           256, 0, stream>>>(x, Wth, Wtl, Qh, Kh, Vt);
    flash_kernel  <<<BATCH*(SEQ/128)*NSPLIT,256, 0, stream>>>(Qh, Kh, Vt, Opart, mlbuf);
    combine_kernel<<<NROW*DIM/8/256,        256, 0, stream>>>(Opart, mlbuf, (float*)d_out);
}